// Round 13
// baseline (32.524 us; speedup 1.0000x reference)
//
#include <hip/hip_runtime.h>
#include <hip/hip_bf16.h>

namespace {

constexpr int KIN  = 32;    // IN_CH
constexpr int KOUT = 64;    // OUT_CH
constexpr int KW   = 9;     // KERNEL
constexpr int KPAD = 4;     // PADDING
constexpr int LIN  = 2048;
constexpr int KTOT = 2592;  // 9 taps * 288 features
constexpr unsigned MAGIC = 0x7F7F7F7Fu;

typedef __bf16 bf16x8 __attribute__((ext_vector_type(8)));
typedef float  f32x4  __attribute__((ext_vector_type(4)));
typedef unsigned short u16x4 __attribute__((ext_vector_type(4)));
typedef unsigned short u16x8 __attribute__((ext_vector_type(8)));

__device__ __forceinline__ unsigned short f2bf(float x) {
    unsigned int u = __float_as_uint(x);
    u += 0x7FFFu + ((u >> 16) & 1u);   // RNE
    return (unsigned short)(u >> 16);
}

__device__ __forceinline__ float bf2f(unsigned short h) {
    return __uint_as_float((unsigned int)h << 16);
}

#define MFMA16(a, b, c) __builtin_amdgcn_mfma_f32_16x16x32_bf16((a), (b), (c), 0, 0, 0)

// ---- single fused kernel: wprep share (blocks 0..80) + features + split-K GEMM ----
constexpr int BN     = 64;
constexpr int TROW   = 72;    // BN + KW - 1
constexpr int F2COLS = 296;   // 592B rows; b128 reads spread uniformly over 32 banks

__global__ __launch_bounds__(512, 4) void kan_all(const float* __restrict__ x,
                                                  const float* __restrict__ base_w,
                                                  const float* __restrict__ spline_w,
                                                  const float* __restrict__ spline_scaler,
                                                  unsigned short* __restrict__ Wf,
                                                  unsigned int* __restrict__ sent,
                                                  float* __restrict__ out) {
    __shared__ __align__(16) char smem[TROW * F2COLS * 2];   // f2t 42624B; red16 aliases 32KB
    unsigned short* f2t = (unsigned short*)smem;

    int tid  = threadIdx.x;
    int lane = tid & 63;
    int wv   = tid >> 6;          // 0..7
    int lo = lane & 15, hi = lane >> 4;

    int blk = blockIdx.x;
    int b   = blk >> 5;
    int l0  = (blk & 31) * BN;

    // ---- wprep share: block ch<81 emits A-fragments for K-chunk ch ----
    // Wf[idx*8+e]: idx=(ch,m,lane'), kappa=ch*32+(lane'>>4)*8+e, o=m*16+(lane'&15)
    if (blk < 81) {
        if (tid < 256) {
            unsigned idx  = (unsigned)blk * 256 + tid;
            unsigned m    = (idx >> 6) & 3;
            unsigned ln   = idx & 63;
            unsigned o    = m * 16 + (ln & 15);
            unsigned kb   = (unsigned)blk * 32 + (ln >> 4) * 8;
            u16x8 pk;
#pragma unroll
            for (int e = 0; e < 8; ++e) {
                unsigned kappa = kb + e;
                unsigned k  = kappa / 288;
                unsigned r2 = kappa - k * 288;
                unsigned i  = r2 / 9;
                unsigned c  = r2 - i * 9;
                unsigned t  = o * 288 + i * 9 + k;
                float val = (c == 0) ? base_w[t]
                                     : spline_w[(size_t)t * 8 + (c - 1)] * spline_scaler[t];
                pk[e] = f2bf(val);
            }
            *(u16x8*)(Wf + (size_t)idx * 8) = pk;
        }
        __builtin_amdgcn_fence(__ATOMIC_RELEASE, "agent");   // flush dirty Wf lines to L3
        __syncthreads();
        if (tid == 0)
            __hip_atomic_store(&sent[blk], MAGIC, __ATOMIC_RELAXED, __HIP_MEMORY_SCOPE_AGENT);
    }

    // ---- hoist x loads (long latency) ahead of LDS zeroing ----
    float vv[5];
#pragma unroll
    for (int p = 0; p < 5; ++p) {
        int unit = p * 512 + tid;
        bool ok = unit < TROW * KIN;
        int i = unit / TROW;
        int r = unit - i * TROW;
        int gx = l0 + r - KPAD;
        vv[p] = 0.f;
        if (ok && gx >= 0 && gx < LIN) vv[p] = x[((size_t)b * KIN + i) * LIN + gx];
    }

    // ---- zero f2t (2664 x 16B) ----
    {
        f32x4 z = (f32x4){0.f, 0.f, 0.f, 0.f};
        for (int c = tid; c < TROW * F2COLS / 8; c += 512)
            *(f32x4*)(f2t + (size_t)c * 8) = z;
    }
    __syncthreads();

    // ---- features: silu + closed-form cubic B-spline, scatter to LDS ----
#pragma unroll
    for (int p = 0; p < 5; ++p) {
        int unit = p * 512 + tid;
        bool ok = unit < TROW * KIN;
        int i = unit / TROW;
        int r = unit - i * TROW;
        float v = vv[p];
        if (ok) {
            unsigned short* row = f2t + (size_t)r * F2COLS + i * 9;
            row[0] = f2bf(v / (1.f + __expf(-v)));             // silu
            float t5 = (v + 2.2f) * 2.5f;                       // knots at -2.2 + 0.4*j
            float mf = floorf(t5);
            int   m  = (int)mf;
            float u  = t5 - mf;
            float u2 = u * u, u3 = u2 * u;
            float w  = 1.f - u;
            float P0 = u3 * (1.f / 6.f);
            float P3 = w * w * w * (1.f / 6.f);
            float P1 = (1.f / 6.f) + 0.5f * u + 0.5f * u2 - 0.5f * u3;
            float P2 = (4.f / 6.f) - u2 + 0.5f * u3;
            int c0 = m - 3;
            if ((unsigned)(c0 + 0) <= 7u) row[1 + c0 + 0] = f2bf(P3);
            if ((unsigned)(c0 + 1) <= 7u) row[1 + c0 + 1] = f2bf(P2);
            if ((unsigned)(c0 + 2) <= 7u) row[1 + c0 + 2] = f2bf(P1);
            if ((unsigned)(c0 + 3) <= 7u) row[1 + c0 + 3] = f2bf(P0);
        }
    }
    __syncthreads();

    // ---- wait for all 81 W-chunks to be published (writers long done by now) ----
    if (tid < 81) {
        while (__hip_atomic_load(&sent[tid], __ATOMIC_RELAXED, __HIP_MEMORY_SCOPE_AGENT) != MAGIC)
            __builtin_amdgcn_s_sleep(2);
    }
    __syncthreads();
    asm volatile("" ::: "memory");   // no Wf load hoists above the spin

    // ---- 8-way split-K: wave wv owns chunks [10*wv, 10*wv+10) of 0..79 ----
    const int ch0 = 10 * wv;
    constexpr int NCHW = 10;

    f32x4 acc[4][4];
#pragma unroll
    for (int m = 0; m < 4; ++m)
#pragma unroll
        for (int n = 0; n < 4; ++n) acc[m][n] = (f32x4){0.f, 0.f, 0.f, 0.f};

    int kk = ch0 / 9;
    int jb = ch0 - kk * 9;
    const unsigned short* wp = Wf + (size_t)ch0 * 2048 + (size_t)lane * 8;
    const unsigned short* fp = f2t + (size_t)(lo + kk) * F2COLS + jb * 32 + hi * 8;

    // prime first chunk
    bf16x8 a0 = *(const bf16x8*)(wp);
    bf16x8 a1 = *(const bf16x8*)(wp + 512);
    bf16x8 a2 = *(const bf16x8*)(wp + 1024);
    bf16x8 a3 = *(const bf16x8*)(wp + 1536);
    bf16x8 b0 = *(const bf16x8*)(fp);
    bf16x8 b1 = *(const bf16x8*)(fp + 16 * F2COLS);
    bf16x8 b2 = *(const bf16x8*)(fp + 32 * F2COLS);
    bf16x8 b3 = *(const bf16x8*)(fp + 48 * F2COLS);

    for (int t = 0; t < NCHW; ++t) {
        // next-chunk pointers (clamped on last iteration -> harmless reload)
        bool last = (t + 1 == NCHW);
        const unsigned short* wpn = last ? wp : wp + 2048;
        int jb2 = last ? jb : jb + 1;
        const unsigned short* fpn = last ? fp : fp + ((jb2 == 9) ? (F2COLS - 8 * 32) : 32);
        if (jb2 == 9) jb2 = 0;

        // prefetch A(t+1) early: full MFMA block below hides L2 latency
        bf16x8 na0 = *(const bf16x8*)(wpn);
        bf16x8 na1 = *(const bf16x8*)(wpn + 512);
        bf16x8 na2 = *(const bf16x8*)(wpn + 1024);
        bf16x8 na3 = *(const bf16x8*)(wpn + 1536);

        __builtin_amdgcn_s_setprio(1);
        // n-major: finish consumers of b_n, then reload b_n in place for t+1
        acc[0][0] = MFMA16(a0, b0, acc[0][0]);
        acc[1][0] = MFMA16(a1, b0, acc[1][0]);
        acc[2][0] = MFMA16(a2, b0, acc[2][0]);
        acc[3][0] = MFMA16(a3, b0, acc[3][0]);
        b0 = *(const bf16x8*)(fpn);
        acc[0][1] = MFMA16(a0, b1, acc[0][1]);
        acc[1][1] = MFMA16(a1, b1, acc[1][1]);
        acc[2][1] = MFMA16(a2, b1, acc[2][1]);
        acc[3][1] = MFMA16(a3, b1, acc[3][1]);
        b1 = *(const bf16x8*)(fpn + 16 * F2COLS);
        acc[0][2] = MFMA16(a0, b2, acc[0][2]);
        acc[1][2] = MFMA16(a1, b2, acc[1][2]);
        acc[2][2] = MFMA16(a2, b2, acc[2][2]);
        acc[3][2] = MFMA16(a3, b2, acc[3][2]);
        b2 = *(const bf16x8*)(fpn + 32 * F2COLS);
        acc[0][3] = MFMA16(a0, b3, acc[0][3]);
        acc[1][3] = MFMA16(a1, b3, acc[1][3]);
        acc[2][3] = MFMA16(a2, b3, acc[2][3]);
        acc[3][3] = MFMA16(a3, b3, acc[3][3]);
        b3 = *(const bf16x8*)(fpn + 48 * F2COLS);
        __builtin_amdgcn_s_setprio(0);

        a0 = na0; a1 = na1; a2 = na2; a3 = na3;
        wp = wpn; fp = fpn; jb = jb2;
    }

    // ---- balanced chunk 80 (kappa 2560..2591, tap 8, j-block 8): 2 MFMA/wave ----
    {
        int mq = wv & 3;                  // m-frag this wave covers
        int np = wv >> 2;                 // n-pair (0: n=0,1; 1: n=2,3)
        bf16x8 a80 = *(const bf16x8*)(Wf + (size_t)80 * 2048 + (size_t)mq * 512 + (size_t)lane * 8);
        const unsigned short* fp80 = f2t + (size_t)(lo + 8) * F2COLS + 8 * 32 + hi * 8;
        bf16x8 bA = *(const bf16x8*)(fp80 + (size_t)(2 * np) * 16 * F2COLS);
        bf16x8 bB = *(const bf16x8*)(fp80 + (size_t)(2 * np + 1) * 16 * F2COLS);
        switch (wv) {   // wave-uniform branch; static acc indices (no scratch)
        case 0: acc[0][0] = MFMA16(a80, bA, acc[0][0]); acc[0][1] = MFMA16(a80, bB, acc[0][1]); break;
        case 1: acc[1][0] = MFMA16(a80, bA, acc[1][0]); acc[1][1] = MFMA16(a80, bB, acc[1][1]); break;
        case 2: acc[2][0] = MFMA16(a80, bA, acc[2][0]); acc[2][1] = MFMA16(a80, bB, acc[2][1]); break;
        case 3: acc[3][0] = MFMA16(a80, bA, acc[3][0]); acc[3][1] = MFMA16(a80, bB, acc[3][1]); break;
        case 4: acc[0][2] = MFMA16(a80, bA, acc[0][2]); acc[0][3] = MFMA16(a80, bB, acc[0][3]); break;
        case 5: acc[1][2] = MFMA16(a80, bA, acc[1][2]); acc[1][3] = MFMA16(a80, bB, acc[1][3]); break;
        case 6: acc[2][2] = MFMA16(a80, bA, acc[2][2]); acc[2][3] = MFMA16(a80, bB, acc[2][3]); break;
        case 7: acc[3][2] = MFMA16(a80, bA, acc[3][2]); acc[3][3] = MFMA16(a80, bB, acc[3][3]); break;
        }
    }

    // ---- 8-way cross-wave reduction, bf16 partials, two 32KB phases ----
    __syncthreads();   // all waves done reading f2t
    unsigned short* red16 = (unsigned short*)smem;
#pragma unroll
    for (int mp = 0; mp < 2; ++mp) {
#pragma unroll
        for (int dm = 0; dm < 2; ++dm)
#pragma unroll
            for (int n = 0; n < 4; ++n) {
                f32x4 a = acc[mp * 2 + dm][n];
                u16x4 pk = (u16x4){f2bf(a[0]), f2bf(a[1]), f2bf(a[2]), f2bf(a[3])};
                *(u16x4*)(red16 + (((size_t)wv * 8 + dm * 4 + n) * 64 + lane) * 4) = pk;
            }
        __syncthreads();
        {
            int dm = wv >> 2, n = wv & 3;
            f32x4 s = (f32x4){0.f, 0.f, 0.f, 0.f};
#pragma unroll
            for (int w = 0; w < 8; ++w) {
                u16x4 pk = *(const u16x4*)(red16 + (((size_t)w * 8 + dm * 4 + n) * 64 + lane) * 4);
                s[0] += bf2f(pk[0]);
                s[1] += bf2f(pk[1]);
                s[2] += bf2f(pk[2]);
                s[3] += bf2f(pk[3]);
            }
            int o = (mp * 2 + dm) * 16 + hi * 4;
            float* op = out + ((size_t)b * KOUT + o) * LIN + l0 + n * 16 + lo;
            op[0]               = s[0];
            op[LIN]             = s[1];
            op[2 * LIN]         = s[2];
            op[3 * (size_t)LIN] = s[3];
        }
        if (mp == 0) __syncthreads();
    }
}

} // namespace

extern "C" void kernel_launch(void* const* d_in, const int* in_sizes, int n_in,
                              void* d_out, int out_size, void* d_ws, size_t ws_size,
                              hipStream_t stream) {
    const float* x             = (const float*)d_in[0];
    const float* base_w        = (const float*)d_in[1];
    const float* spline_w      = (const float*)d_in[2];
    const float* spline_scaler = (const float*)d_in[3];
    float* out = (float*)d_out;

    unsigned short* Wf  = (unsigned short*)d_ws;                    // 331776 B
    unsigned int*  sent = (unsigned int*)((char*)d_ws + 331776);    // 81 x u32

    kan_all<<<512, 512, 0, stream>>>(x, base_w, spline_w, spline_scaler, Wf, sent, out);
}

// Round 14
// 22.886 us; speedup vs baseline: 1.4211x; 1.4211x over previous
//
#include <hip/hip_runtime.h>
#include <hip/hip_bf16.h>

namespace {

constexpr int KIN  = 32;    // IN_CH
constexpr int KOUT = 64;    // OUT_CH
constexpr int KW   = 9;     // KERNEL
constexpr int KPAD = 4;     // PADDING
constexpr int LIN  = 2048;
constexpr int KTOT = 2592;  // 9 taps * 288 features

typedef __bf16 bf16x8 __attribute__((ext_vector_type(8)));
typedef float  f32x4  __attribute__((ext_vector_type(4)));
typedef unsigned short u16x4 __attribute__((ext_vector_type(4)));
typedef unsigned short u16x8 __attribute__((ext_vector_type(8)));

__device__ __forceinline__ unsigned short f2bf(float x) {
    unsigned int u = __float_as_uint(x);
    u += 0x7FFFu + ((u >> 16) & 1u);   // RNE
    return (unsigned short)(u >> 16);
}

__device__ __forceinline__ float bf2f(unsigned short h) {
    return __uint_as_float((unsigned int)h << 16);
}

#define MFMA16(a, b, c) __builtin_amdgcn_mfma_f32_16x16x32_bf16((a), (b), (c), 0, 0, 0)

// ---- kernel 1: weights -> MFMA-fragment order, output-coalesced (R12) ----
// Thread owns one 16B slot: idx=(ch,m,lane); writes Wf[idx*8 .. idx*8+7]
// where element e has kappa = ch*32 + (lane>>4)*8 + e, o = m*16 + (lane&15).
__global__ __launch_bounds__(256) void kan_wprep(const float* __restrict__ base_w,
                                                 const float* __restrict__ spline_w,
                                                 const float* __restrict__ spline_scaler,
                                                 unsigned short* __restrict__ Wf) {
    unsigned int idx = blockIdx.x * 256 + threadIdx.x;    // < 81*4*64 = 20736
    unsigned int ch  = idx >> 8;          // 0..80
    unsigned int m   = (idx >> 6) & 3;    // o-block
    unsigned int lane = idx & 63;
    unsigned int o  = m * 16 + (lane & 15);
    unsigned int kb = ch * 32 + (lane >> 4) * 8;   // first kappa of this slot

    u16x8 pk;
#pragma unroll
    for (int e = 0; e < 8; ++e) {
        unsigned int kappa = kb + e;
        unsigned int k  = kappa / 288;        // conv tap
        unsigned int r2 = kappa - k * 288;
        unsigned int i  = r2 / 9;             // in-channel
        unsigned int c  = r2 - i * 9;         // 0 = silu, 1..8 = spline coef
        unsigned int t  = o * 288 + i * 9 + k;
        float val = (c == 0) ? base_w[t]
                             : spline_w[(size_t)t * 8 + (c - 1)] * spline_scaler[t];
        pk[e] = f2bf(val);
    }
    *(u16x8*)(Wf + (size_t)idx * 8) = pk;
}

// ---- kernel 2: fused features + barrier-free 8-way split-K, balanced ----
constexpr int BN     = 64;
constexpr int TROW   = 72;    // BN + KW - 1
constexpr int F2COLS = 296;   // 592B rows; b128 reads spread 2-way max (free)

__global__ __launch_bounds__(512, 4) void kan_fused(const float* __restrict__ x,
                                                    const unsigned short* __restrict__ Wf,
                                                    float* __restrict__ out) {
    __shared__ __align__(16) char smem[65536];   // f2t 42624B / red16 64KB (aliased)
    unsigned short* f2t = (unsigned short*)smem;

    int tid  = threadIdx.x;
    int lane = tid & 63;
    int wv   = tid >> 6;          // 0..7
    int lo = lane & 15, hi = lane >> 4;

    int blk = blockIdx.x;
    int b   = blk >> 5;
    int l0  = (blk & 31) * BN;

    // ---- split-K geometry + prime-A hoist (L2 latency hides under LDS phases) ----
    const int ch0 = 10 * wv;
    constexpr int NCHW = 10;
    int kk = ch0 / 9;
    int jb = ch0 - kk * 9;
    const unsigned short* wp = Wf + (size_t)ch0 * 2048 + (size_t)lane * 8;
    bf16x8 a0 = *(const bf16x8*)(wp);
    bf16x8 a1 = *(const bf16x8*)(wp + 512);
    bf16x8 a2 = *(const bf16x8*)(wp + 1024);
    bf16x8 a3 = *(const bf16x8*)(wp + 1536);

    // ---- hoist x loads (long latency) ahead of LDS zeroing ----
    float vv[5];
#pragma unroll
    for (int p = 0; p < 5; ++p) {
        int unit = p * 512 + tid;
        bool ok = unit < TROW * KIN;
        int i = unit / TROW;
        int r = unit - i * TROW;
        int gx = l0 + r - KPAD;
        vv[p] = 0.f;
        if (ok && gx >= 0 && gx < LIN) vv[p] = x[((size_t)b * KIN + i) * LIN + gx];
    }

    // ---- zero f2t (2664 x 16B) ----
    {
        f32x4 z = (f32x4){0.f, 0.f, 0.f, 0.f};
        for (int c = tid; c < TROW * F2COLS / 8; c += 512)
            *(f32x4*)(f2t + (size_t)c * 8) = z;
    }
    __syncthreads();

    // ---- features: silu + closed-form cubic B-spline, scatter to LDS ----
#pragma unroll
    for (int p = 0; p < 5; ++p) {
        int unit = p * 512 + tid;
        bool ok = unit < TROW * KIN;
        int i = unit / TROW;
        int r = unit - i * TROW;
        float v = vv[p];
        if (ok) {
            unsigned short* row = f2t + (size_t)r * F2COLS + i * 9;
            row[0] = f2bf(v / (1.f + __expf(-v)));             // silu
            float t5 = (v + 2.2f) * 2.5f;                       // knots at -2.2 + 0.4*j
            float mf = floorf(t5);
            int   m  = (int)mf;
            float u  = t5 - mf;
            float u2 = u * u, u3 = u2 * u;
            float w  = 1.f - u;
            float P0 = u3 * (1.f / 6.f);
            float P3 = w * w * w * (1.f / 6.f);
            float P1 = (1.f / 6.f) + 0.5f * u + 0.5f * u2 - 0.5f * u3;
            float P2 = (4.f / 6.f) - u2 + 0.5f * u3;
            int c0 = m - 3;
            if ((unsigned)(c0 + 0) <= 7u) row[1 + c0 + 0] = f2bf(P3);
            if ((unsigned)(c0 + 1) <= 7u) row[1 + c0 + 1] = f2bf(P2);
            if ((unsigned)(c0 + 2) <= 7u) row[1 + c0 + 2] = f2bf(P1);
            if ((unsigned)(c0 + 3) <= 7u) row[1 + c0 + 3] = f2bf(P0);
        }
    }
    __syncthreads();

    // ---- 8-way split-K: wave wv owns chunks [10*wv, 10*wv+10) of 0..79 ----
    f32x4 acc[4][4];
#pragma unroll
    for (int m = 0; m < 4; ++m)
#pragma unroll
        for (int n = 0; n < 4; ++n) acc[m][n] = (f32x4){0.f, 0.f, 0.f, 0.f};

    const unsigned short* fp = f2t + (size_t)(lo + kk) * F2COLS + jb * 32 + hi * 8;
    bf16x8 b0 = *(const bf16x8*)(fp);
    bf16x8 b1 = *(const bf16x8*)(fp + 16 * F2COLS);
    bf16x8 b2 = *(const bf16x8*)(fp + 32 * F2COLS);
    bf16x8 b3 = *(const bf16x8*)(fp + 48 * F2COLS);

    for (int t = 0; t < NCHW; ++t) {
        // next-chunk pointers (clamped on last iteration -> harmless reload)
        bool last = (t + 1 == NCHW);
        const unsigned short* wpn = last ? wp : wp + 2048;
        int jb2 = last ? jb : jb + 1;
        const unsigned short* fpn = last ? fp : fp + ((jb2 == 9) ? (F2COLS - 8 * 32) : 32);
        if (jb2 == 9) jb2 = 0;

        // prefetch A(t+1) early: full MFMA block below hides L2 latency
        bf16x8 na0 = *(const bf16x8*)(wpn);
        bf16x8 na1 = *(const bf16x8*)(wpn + 512);
        bf16x8 na2 = *(const bf16x8*)(wpn + 1024);
        bf16x8 na3 = *(const bf16x8*)(wpn + 1536);

        __builtin_amdgcn_s_setprio(1);
        // n-major: finish consumers of b_n, then reload b_n in place for t+1
        acc[0][0] = MFMA16(a0, b0, acc[0][0]);
        acc[1][0] = MFMA16(a1, b0, acc[1][0]);
        acc[2][0] = MFMA16(a2, b0, acc[2][0]);
        acc[3][0] = MFMA16(a3, b0, acc[3][0]);
        b0 = *(const bf16x8*)(fpn);
        acc[0][1] = MFMA16(a0, b1, acc[0][1]);
        acc[1][1] = MFMA16(a1, b1, acc[1][1]);
        acc[2][1] = MFMA16(a2, b1, acc[2][1]);
        acc[3][1] = MFMA16(a3, b1, acc[3][1]);
        b1 = *(const bf16x8*)(fpn + 16 * F2COLS);
        acc[0][2] = MFMA16(a0, b2, acc[0][2]);
        acc[1][2] = MFMA16(a1, b2, acc[1][2]);
        acc[2][2] = MFMA16(a2, b2, acc[2][2]);
        acc[3][2] = MFMA16(a3, b2, acc[3][2]);
        b2 = *(const bf16x8*)(fpn + 32 * F2COLS);
        acc[0][3] = MFMA16(a0, b3, acc[0][3]);
        acc[1][3] = MFMA16(a1, b3, acc[1][3]);
        acc[2][3] = MFMA16(a2, b3, acc[2][3]);
        acc[3][3] = MFMA16(a3, b3, acc[3][3]);
        b3 = *(const bf16x8*)(fpn + 48 * F2COLS);
        __builtin_amdgcn_s_setprio(0);

        a0 = na0; a1 = na1; a2 = na2; a3 = na3;
        wp = wpn; fp = fpn; jb = jb2;
    }

    // ---- balanced chunk 80 (kappa 2560..2591, tap 8, j-block 8): 2 MFMA/wave ----
    {
        int mq = wv & 3;                  // m-frag this wave covers
        int np = wv >> 2;                 // n-pair (0: n=0,1; 1: n=2,3)
        bf16x8 a80 = *(const bf16x8*)(Wf + (size_t)80 * 2048 + (size_t)mq * 512 + (size_t)lane * 8);
        const unsigned short* fp80 = f2t + (size_t)(lo + 8) * F2COLS + 8 * 32 + hi * 8;
        bf16x8 bA = *(const bf16x8*)(fp80 + (size_t)(2 * np) * 16 * F2COLS);
        bf16x8 bB = *(const bf16x8*)(fp80 + (size_t)(2 * np + 1) * 16 * F2COLS);
        switch (wv) {   // wave-uniform branch; static acc indices (no scratch)
        case 0: acc[0][0] = MFMA16(a80, bA, acc[0][0]); acc[0][1] = MFMA16(a80, bB, acc[0][1]); break;
        case 1: acc[1][0] = MFMA16(a80, bA, acc[1][0]); acc[1][1] = MFMA16(a80, bB, acc[1][1]); break;
        case 2: acc[2][0] = MFMA16(a80, bA, acc[2][0]); acc[2][1] = MFMA16(a80, bB, acc[2][1]); break;
        case 3: acc[3][0] = MFMA16(a80, bA, acc[3][0]); acc[3][1] = MFMA16(a80, bB, acc[3][1]); break;
        case 4: acc[0][2] = MFMA16(a80, bA, acc[0][2]); acc[0][3] = MFMA16(a80, bB, acc[0][3]); break;
        case 5: acc[1][2] = MFMA16(a80, bA, acc[1][2]); acc[1][3] = MFMA16(a80, bB, acc[1][3]); break;
        case 6: acc[2][2] = MFMA16(a80, bA, acc[2][2]); acc[2][3] = MFMA16(a80, bB, acc[2][3]); break;
        case 7: acc[3][2] = MFMA16(a80, bA, acc[3][2]); acc[3][3] = MFMA16(a80, bB, acc[3][3]); break;
        }
    }

    // ---- single-phase 8-way cross-wave reduction, bf16 partials (64KB exact) ----
    __syncthreads();   // all waves done reading f2t
    unsigned short* red16 = (unsigned short*)smem;
#pragma unroll
    for (int m = 0; m < 4; ++m)
#pragma unroll
        for (int n = 0; n < 4; ++n) {
            int sid = m * 4 + n;
            f32x4 a = acc[m][n];
            u16x4 pk = (u16x4){f2bf(a[0]), f2bf(a[1]), f2bf(a[2]), f2bf(a[3])};
            *(u16x4*)(red16 + (((size_t)sid * 8 + wv) * 64 + lane) * 4) = pk;
        }
    __syncthreads();
#pragma unroll
    for (int s = 0; s < 2; ++s) {
        int sid = wv * 2 + s;
        int m = sid >> 2, n = sid & 3;
        f32x4 acc_s = (f32x4){0.f, 0.f, 0.f, 0.f};
#pragma unroll
        for (int w = 0; w < 8; ++w) {
            u16x4 pk = *(const u16x4*)(red16 + (((size_t)sid * 8 + w) * 64 + lane) * 4);
            acc_s[0] += bf2f(pk[0]);
            acc_s[1] += bf2f(pk[1]);
            acc_s[2] += bf2f(pk[2]);
            acc_s[3] += bf2f(pk[3]);
        }
        int o = m * 16 + hi * 4;
        float* op = out + ((size_t)b * KOUT + o) * LIN + l0 + n * 16 + lo;
        op[0]               = acc_s[0];
        op[LIN]             = acc_s[1];
        op[2 * LIN]         = acc_s[2];
        op[3 * (size_t)LIN] = acc_s[3];
    }
}

} // namespace

extern "C" void kernel_launch(void* const* d_in, const int* in_sizes, int n_in,
                              void* d_out, int out_size, void* d_ws, size_t ws_size,
                              hipStream_t stream) {
    const float* x             = (const float*)d_in[0];
    const float* base_w        = (const float*)d_in[1];
    const float* spline_w      = (const float*)d_in[2];
    const float* spline_scaler = (const float*)d_in[3];
    float* out = (float*)d_out;

    unsigned short* Wf = (unsigned short*)d_ws;   // 81*4*64*8 u16 = 331776 B

    kan_wprep<<<81, 256, 0, stream>>>(base_w, spline_w, spline_scaler, Wf);
    kan_fused<<<512, 512, 0, stream>>>(x, Wf, out);
}